// Round 1
// baseline (210.082 us; speedup 1.0000x reference)
//
#include <hip/hip_runtime.h>

#define HID 768
#define NTHREADS 256
#define NWAVES 4   // 256/64

// One block per token. Stage h[t] in LDS; each wave handles path steps
// d = wave, wave+4, ... Each step: gather W[n] (H x 2 f32) with coalesced
// float4 loads, dot against h, wave-reduce, double-softmax CE on lane 0.
__global__ __launch_bounds__(NTHREADS) void huffman_loss_kernel(
    const float* __restrict__ hidden,       // [T, H]
    const int*   __restrict__ target,       // [T]
    const float* __restrict__ node_W,       // [V-1, H, 2]
    const float* __restrict__ node_b,       // [V-1, 2]
    const int*   __restrict__ path_nodes,   // [V, D]
    const int*   __restrict__ path_bits,    // [V, D]
    const void*  __restrict__ path_mask,    // [V, D] bool (byte OR int32 layout)
    float*       __restrict__ out,          // [1]
    int D)
{
    __shared__ float sh[HID];

    const int t   = blockIdx.x;
    const int tid = threadIdx.x;

    // Detect mask storage layout. mask[0,0..3] are all true (min path depth
    // >> 4 for this tree), so byte layout reads 0x01010101 here; int32
    // layout reads 1.
    const bool mask_is_byte = (*(const unsigned int*)path_mask) > 1u;
    const unsigned char* pm8 = (const unsigned char*)path_mask;
    const int*           pm32 = (const int*)path_mask;

    // Stage hidden row into LDS (768 floats, 3 loads/thread).
    const float* hrow = hidden + (size_t)t * HID;
    for (int i = tid; i < HID; i += NTHREADS) sh[i] = hrow[i];
    __syncthreads();

    const int wave = tid >> 6;
    const int lane = tid & 63;
    const int v    = target[t];
    const size_t prow = (size_t)v * D;

    float lsum = 0.0f;

    for (int d = wave; d < D; d += NWAVES) {
        // Valid steps are a contiguous prefix -> once false, all later d
        // (including d+NWAVES) are false.
        const bool valid = mask_is_byte ? (pm8[prow + d] != 0)
                                        : (pm32[prow + d] != 0);
        if (!valid) break;

        const int n = path_nodes[prow + d];
        const float4* __restrict__ w4 =
            (const float4*)(node_W + (size_t)n * (HID * 2));
        const float2* __restrict__ h2 = (const float2*)sh;

        float acc0 = 0.0f, acc1 = 0.0f;
        #pragma unroll
        for (int j = 0; j < HID / 2 / 64; ++j) {   // 6 iters
            const int p = j * 64 + lane;           // k-pair index: k = 2p, 2p+1
            const float4 w = w4[p];                // W[n,2p,0],W[n,2p,1],W[n,2p+1,0],W[n,2p+1,1]
            const float2 h = h2[p];
            acc0 += h.x * w.x + h.y * w.z;
            acc1 += h.x * w.y + h.y * w.w;
        }

        // 64-lane butterfly reduction.
        #pragma unroll
        for (int off = 32; off > 0; off >>= 1) {
            acc0 += __shfl_xor(acc0, off, 64);
            acc1 += __shfl_xor(acc1, off, 64);
        }

        if (lane == 0) {
            const float l0 = acc0 + node_b[n * 2 + 0];
            const float l1 = acc1 + node_b[n * 2 + 1];
            // probs = softmax(l)
            const float m  = fmaxf(l0, l1);
            const float e0 = __expf(l0 - m);
            const float e1 = __expf(l1 - m);
            const float s  = e0 + e1;
            const float p0 = e0 / s;
            const float p1 = e1 / s;
            // ce = -log_softmax(probs)[bit] = lse(p0,p1) - p_bit
            const float lse = __logf(__expf(p0) + __expf(p1));
            const float pb  = path_bits[prow + d] ? p1 : p0;
            lsum += lse - pb;
        }
    }

    if (lane == 0 && lsum != 0.0f) atomicAdd(out, lsum);
}

extern "C" void kernel_launch(void* const* d_in, const int* in_sizes, int n_in,
                              void* d_out, int out_size, void* d_ws, size_t ws_size,
                              hipStream_t stream) {
    const float* hidden     = (const float*)d_in[0];
    const int*   target     = (const int*)d_in[1];
    const float* node_W     = (const float*)d_in[2];
    const float* node_b     = (const float*)d_in[3];
    const int*   path_nodes = (const int*)d_in[4];
    const int*   path_bits  = (const int*)d_in[5];
    const void*  path_mask  = (const void*)d_in[6];
    float* out = (float*)d_out;

    const int T   = in_sizes[0] / HID;        // B*S = 2048
    const int Vm1 = in_sizes[3] / 2;          // V-1
    const int V   = Vm1 + 1;
    const int D   = in_sizes[4] / V;          // padded path depth

    // d_out is re-poisoned (0xAA) before every timed call; we accumulate
    // with atomics, so zero it first (memset node is graph-capture legal).
    hipMemsetAsync(d_out, 0, sizeof(float), stream);

    huffman_loss_kernel<<<dim3(T), dim3(NTHREADS), 0, stream>>>(
        hidden, target, node_W, node_b, path_nodes, path_bits, path_mask,
        out, D);
}

// Round 2
// 129.398 us; speedup vs baseline: 1.6235x; 1.6235x over previous
//
#include <hip/hip_runtime.h>

#define HID 768
#define NTHREADS 256
#define WPB 4          // waves per block
#define RTHREADS 256   // reduce kernel block size

// One wave per (token, path-step). Wave w of block (bx,by) handles
// t = bx, d = by*4 + w. Each wave: gather W[path_nodes[target[t]][d]]
// (H x 2 f32, 6 coalesced float4 loads/lane), dot against h[t] (loaded
// straight from global, independent of the gather chain), 64-lane
// butterfly, double-softmax CE, one float written to partial[].
// No LDS, no __syncthreads, no atomics.
__global__ __launch_bounds__(NTHREADS) void huffman_step_kernel(
    const float* __restrict__ hidden,       // [T, H]
    const int*   __restrict__ target,       // [T]
    const float* __restrict__ node_W,       // [V-1, H, 2]
    const float* __restrict__ node_b,       // [V-1, 2]
    const int*   __restrict__ path_nodes,   // [V, D]
    const int*   __restrict__ path_bits,    // [V, D]
    const void*  __restrict__ path_mask,    // [V, D] bool (byte OR int32 layout)
    float*       __restrict__ partial,      // [gridDim.x * gridDim.y * WPB]
    int D)
{
    const int t    = blockIdx.x;
    const int wave = threadIdx.x >> 6;
    const int lane = threadIdx.x & 63;
    const int d    = blockIdx.y * WPB + wave;
    const int slot = (blockIdx.x * gridDim.y + blockIdx.y) * WPB + wave;

    float result = 0.0f;

    if (d < D) {
        // Mask layout detect: mask[0,0..3] all true (min Huffman depth >> 4),
        // so byte layout reads 0x01010101, int32 layout reads 1.
        const bool mask_is_byte = (*(const unsigned int*)path_mask) > 1u;

        const int v = target[t];                       // scalar (block-uniform)
        const long prow = (long)v * D + d;
        const bool valid = mask_is_byte
            ? (((const unsigned char*)path_mask)[prow] != 0)
            : (((const int*)path_mask)[prow] != 0);

        if (valid) {
            const int n = path_nodes[prow];
            const float4* __restrict__ w4 =
                (const float4*)(node_W + (long)n * (HID * 2));
            const float2* __restrict__ h2 =
                (const float2*)(hidden + (long)t * HID);

            float acc0 = 0.0f, acc1 = 0.0f;
            #pragma unroll
            for (int j = 0; j < HID / 2 / 64; ++j) {   // 6 iters
                const int p = j * 64 + lane;           // k-pair: k = 2p, 2p+1
                const float4 w = w4[p];                // W[n,2p,{0,1}],W[n,2p+1,{0,1}]
                const float2 h = h2[p];
                acc0 += h.x * w.x + h.y * w.z;
                acc1 += h.x * w.y + h.y * w.w;
            }

            #pragma unroll
            for (int off = 32; off > 0; off >>= 1) {
                acc0 += __shfl_xor(acc0, off, 64);
                acc1 += __shfl_xor(acc1, off, 64);
            }

            // All lanes hold the full dots now; compute CE redundantly.
            const float l0 = acc0 + node_b[n * 2 + 0];
            const float l1 = acc1 + node_b[n * 2 + 1];
            const float m  = fmaxf(l0, l1);
            const float e0 = __expf(l0 - m);
            const float e1 = __expf(l1 - m);
            const float s  = e0 + e1;
            const float p0 = e0 / s;
            const float p1 = e1 / s;
            const float lse = __logf(__expf(p0) + __expf(p1));
            const float pb  = path_bits[prow] ? p1 : p0;
            result = lse - pb;
        }
    }

    if (lane == 0) partial[slot] = result;   // every slot written (ws is poisoned)
}

// Single-block reduce of n floats (n % 4 == 0) -> out[0].
__global__ __launch_bounds__(RTHREADS) void huffman_reduce_kernel(
    const float* __restrict__ partial, float* __restrict__ out, int n4)
{
    const float4* __restrict__ p4 = (const float4*)partial;
    float s = 0.0f;
    for (int i = threadIdx.x; i < n4; i += RTHREADS) {
        const float4 v = p4[i];
        s += (v.x + v.y) + (v.z + v.w);
    }
    #pragma unroll
    for (int off = 32; off > 0; off >>= 1) s += __shfl_xor(s, off, 64);
    __shared__ float ws[RTHREADS / 64];
    if ((threadIdx.x & 63) == 0) ws[threadIdx.x >> 6] = s;
    __syncthreads();
    if (threadIdx.x == 0) {
        float tot = 0.0f;
        #pragma unroll
        for (int w = 0; w < RTHREADS / 64; ++w) tot += ws[w];
        out[0] = tot;
    }
}

extern "C" void kernel_launch(void* const* d_in, const int* in_sizes, int n_in,
                              void* d_out, int out_size, void* d_ws, size_t ws_size,
                              hipStream_t stream) {
    const float* hidden     = (const float*)d_in[0];
    const int*   target     = (const int*)d_in[1];
    const float* node_W     = (const float*)d_in[2];
    const float* node_b     = (const float*)d_in[3];
    const int*   path_nodes = (const int*)d_in[4];
    const int*   path_bits  = (const int*)d_in[5];
    const void*  path_mask  = (const void*)d_in[6];
    float* out = (float*)d_out;
    float* partial = (float*)d_ws;

    const int T   = in_sizes[0] / HID;        // B*S = 2048
    const int Vm1 = in_sizes[3] / 2;          // V-1
    const int V   = Vm1 + 1;
    const int D   = in_sizes[4] / V;          // padded path depth (~20)

    const int gy    = (D + WPB - 1) / WPB;    // step-groups per token
    const int nslot = T * gy * WPB;           // multiple of 4

    huffman_step_kernel<<<dim3(T, gy), dim3(NTHREADS), 0, stream>>>(
        hidden, target, node_W, node_b, path_nodes, path_bits, path_mask,
        partial, D);

    huffman_reduce_kernel<<<dim3(1), dim3(RTHREADS), 0, stream>>>(
        partial, out, nslot / 4);
}